// Round 1
// baseline (125.240 us; speedup 1.0000x reference)
//
#include <hip/hip_runtime.h>

#define IMG_H 512
#define IMG_W 512
#define NPLANES 24          // N*C = 8*3
#define ROWS_PER_BLK 32     // output rows per block
#define STRIPW 256          // columns per block (one thread per column)
#define NITER 42            // ROWS_PER_BLK + 10 halo rows
#define TOTAL_PIX 6291456.0f // 8*3*512*512

// Gaussian window, sigma=1.5, K=11, normalized (matches jnp reference to ~1e-7)
__device__ __constant__ float GW[11] = {
    0.00102838f, 0.00759876f, 0.03600050f, 0.10935817f, 0.21300535f,
    0.26601172f, 0.21300535f, 0.10935817f, 0.03600050f, 0.00759876f,
    0.00102838f};

extern "C" __global__ __launch_bounds__(256) void ssim_structure_kernel(
    const float* __restrict__ x, const float* __restrict__ y,
    float* __restrict__ accum) {
  const int tid = threadIdx.x;
  const int chunk = blockIdx.x;  // 0..15  (row chunk)
  const int strip = blockIdx.y;  // 0..1   (column strip)
  const int plane = blockIdx.z;  // 0..23

  const size_t pbase = (size_t)plane * IMG_H * IMG_W;
  const float* __restrict__ xp = x + pbase;
  const float* __restrict__ yp = y + pbase;
  const int cbase = strip * STRIPW;
  const int r0 = chunk * ROWS_PER_BLK;

  // double-buffered staging row: 266 needed (256 + 10 halo), pad to 272
  __shared__ float2 lrow[2][STRIPW + 16];

  // circular register buffers of horizontal sums (indices compile-time via
  // the unroll-by-11 trick below)
  float bx[11], by[11], bxx[11], byy[11], bxy[11];

  float acc = 0.0f;

  // ---- row loader (prefetch into registers) ----
  const int gc = cbase - 5 + tid;        // main element column
  const int gc2 = gc + STRIPW;           // halo element column (tid < 10)
  float2 pre_m, pre_e;

  auto loadrow = [&](int i, float2& m, float2& e) {
    const int hr = r0 - 5 + i;
    const bool rvalid = (i < NITER) & (hr >= 0) & (hr < IMG_H);
    float xv = 0.f, yv = 0.f, xe = 0.f, ye = 0.f;
    if (rvalid) {
      const int rowoff = hr * IMG_W;
      if (gc >= 0 && gc < IMG_W) {
        xv = xp[rowoff + gc];
        yv = yp[rowoff + gc];
      }
      if (tid < 10 && gc2 < IMG_W) {  // gc2 >= 0 always
        xe = xp[rowoff + gc2];
        ye = yp[rowoff + gc2];
      }
    }
    m = make_float2(xv, yv);
    e = make_float2(xe, ye);
  };

  loadrow(0, pre_m, pre_e);

  for (int ob = 0; ob < 4; ++ob) {  // 4 * 11 = 44 iterations (42 useful)
#pragma unroll
    for (int ii = 0; ii < 11; ++ii) {
      const int i = ob * 11 + ii;
      const int sel = i & 1;

      // stage prefetched row into LDS
      lrow[sel][tid] = pre_m;
      if (tid < 10) lrow[sel][STRIPW + tid] = pre_e;
      __syncthreads();

      // prefetch next row (hides global latency behind compute)
      loadrow(i + 1, pre_m, pre_e);

      // horizontal pass -> circular slot ii (== i % 11)
      if (i < NITER) {
        float tx = 0.f, ty = 0.f, txx = 0.f, tyy = 0.f, txy = 0.f;
#pragma unroll
        for (int d = 0; d < 11; ++d) {
          const float2 v = lrow[sel][tid + d];
          const float wgt = GW[d];
          const float wx = wgt * v.x;
          const float wy = wgt * v.y;
          tx += wx;
          ty += wy;
          txx = fmaf(wx, v.x, txx);
          txy = fmaf(wx, v.y, txy);
          tyy = fmaf(wy, v.y, tyy);
        }
        bx[ii] = tx;
        by[ii] = ty;
        bxx[ii] = txx;
        byy[ii] = tyy;
        bxy[ii] = txy;
      }

      // vertical pass + epilogue for output row r0 + (i - 10)
      if (i >= 10 && i < NITER) {
        float vx = 0.f, vy = 0.f, vxx = 0.f, vyy = 0.f, vxy = 0.f;
#pragma unroll
        for (int k = 0; k < 11; ++k) {
          const int s = (ii + 1 + k) % 11;  // compile-time after unroll
          const float wgt = GW[k];
          vx = fmaf(wgt, bx[s], vx);
          vy = fmaf(wgt, by[s], vy);
          vxx = fmaf(wgt, bxx[s], vxx);
          vyy = fmaf(wgt, byy[s], vyy);
          vxy = fmaf(wgt, bxy[s], vxy);
        }
        const float sxy = vxy - vx * vy;
        const float sxx = fmaxf(vxx - vx * vx, 1e-12f);
        const float syy = fmaxf(vyy - vy * vy, 1e-12f);
        const float denom = sqrtf(sxx) * sqrtf(syy) + 1e-4f;
        acc += (sxy + 1e-4f) / denom;
      }
    }
  }

  // ---- block reduction: wave shuffle then cross-wave LDS ----
#pragma unroll
  for (int off = 32; off > 0; off >>= 1) acc += __shfl_down(acc, off, 64);
  __shared__ float wsum[4];
  if ((tid & 63) == 0) wsum[tid >> 6] = acc;
  __syncthreads();
  if (tid == 0) {
    atomicAdd(accum, wsum[0] + wsum[1] + wsum[2] + wsum[3]);
  }
}

extern "C" __global__ void ssim_finalize_kernel(const float* __restrict__ accum,
                                                float* __restrict__ out) {
  out[0] = 1.0f - accum[0] * (1.0f / TOTAL_PIX);
}

extern "C" void kernel_launch(void* const* d_in, const int* in_sizes, int n_in,
                              void* d_out, int out_size, void* d_ws,
                              size_t ws_size, hipStream_t stream) {
  const float* x = (const float*)d_in[0];
  const float* y = (const float*)d_in[1];
  float* out = (float*)d_out;
  float* accum = (float*)d_ws;

  hipMemsetAsync(accum, 0, sizeof(float), stream);

  dim3 grid(IMG_H / ROWS_PER_BLK, IMG_W / STRIPW, NPLANES);  // 16 x 2 x 24
  ssim_structure_kernel<<<grid, 256, 0, stream>>>(x, y, accum);
  ssim_finalize_kernel<<<1, 1, 0, stream>>>(accum, out);
}